// Round 9
// baseline (190.219 us; speedup 1.0000x reference)
//
#include <hip/hip_runtime.h>
#include <math.h>

#define T_LEN 512
#define B_N   1024
#define K_N   48
#define START_TAG (K_N - 2)
#define STOP_TAG  (K_N - 1)
#define NEG   -10000.0f

// Forward/backward split CRF + LPT at 1 wave/SIMD, HYBRID broadcast engine.
//
// R8 insight: the two broadcast mechanisms saturate DIFFERENT hardware:
//   * v_readlane rides the per-SIMD VALU (R6 engine: 689 cy/step, VALU-bound)
//   * ds_bpermute rides the per-CU LDS crossbar, SHARED by all 4 SIMDs
//     (R8 engine: 655 cy/step = 4 waves x 46 ops x ~3cy LDS time per CU).
// A solo wave issues <=1 instr/cy either way, but the EXECUTION of the two
// halves overlaps across the two resources. Balanced split (x ~ 0.5):
//   24 broadcasts via ds_bpermute (DS pipe) + 22 via v_readlane (VALU),
//   interleaved 2:2 into 4 accumulator chains.
// Predicted pace ~ max(VALU ~270, CU-LDS ~280) + tail ~ 450-550 cy/step.
//
// Carried, load-bearing (R0-R8):
//  * R6/R8 step semantics exactly; renorm every 4 steps (representation-only,
//    safe while frozen; R7's per-step folded renorm was -8%).
//  * 46 k-terms; step 0 peeled closed-form (k=46 START only feeds t=0;
//    k=47 STOP col = exp(-1e4) = 0).
//  * LPT counting sort, longest-first; fwd/bwd pair balanced to +-1 step.
//  * waves_per_eu(1,1): solo wave/SIMD (W=2 readlane contention was 1.7x
//    per-wave pace, R4 — retest only if issue-port becomes the proven floor).
//  * unconditional clamped loads, 8-ahead static ping-pong; unmasked bulk
//    blocks + one masked tail; no barrier on the recursion chain.

__device__ __forceinline__ float bcast(float v, int k) {
    return __uint_as_float(__builtin_amdgcn_readlane(__float_as_uint(v), k));
}

// w_lane = sum_{k<46} E[lane,k] * (lane k of src).
// DS half: k = 0..23 (24 ds_bpermute). VALU half: k = 24..45 (22 readlane).
// Interleaved so the scheduler can keep both resources fed.
__device__ __forceinline__ float matvec46(const float (&E)[46], float src) {
    const int qb = __float_as_int(src);
    float a0 = 0.f, a1 = 0.f, a2 = 0.f, a3 = 0.f;
    #pragma unroll
    for (int i = 0; i < 11; ++i) {
        const int kd0 = 2 * i,      kd1 = 2 * i + 1;   // 0..21  (DS)
        const int kr0 = 24 + 2 * i, kr1 = 25 + 2 * i;  // 24..45 (VALU)
        const float s0 = __int_as_float(__builtin_amdgcn_ds_bpermute(4 * kd0, qb));
        const float s1 = __int_as_float(__builtin_amdgcn_ds_bpermute(4 * kd1, qb));
        const float r0 = bcast(src, kr0);
        const float r1 = bcast(src, kr1);
        a0 = fmaf(E[kd0], s0, a0);
        a1 = fmaf(E[kd1], s1, a1);
        a2 = fmaf(E[kr0], r0, a2);
        a3 = fmaf(E[kr1], r1, a3);
    }
    {   // DS remainder: k = 22, 23
        const float s0 = __int_as_float(__builtin_amdgcn_ds_bpermute(4 * 22, qb));
        const float s1 = __int_as_float(__builtin_amdgcn_ds_bpermute(4 * 23, qb));
        a0 = fmaf(E[22], s0, a0);
        a1 = fmaf(E[23], s1, a1);
    }
    return (a0 + a1) + (a2 + a3);
}

// Representation change only: q /= q_0, C += log(q_0). Safe while frozen.
__device__ __forceinline__ void renorm(float& q, float& C) {
    const float g = bcast(q, 0);
    C += __logf(g);
    q *= __builtin_amdgcn_rcpf(g);
}

// Run `steps` recursion steps. BWD=0: q' = exp(f) * (E q), rows rbase,+1,...
// BWD=1: q' = E^T (exp(f) .* q), rows rbase,-1,...
template <int BWD>
__device__ __forceinline__ void run_chain(const float* __restrict__ fb,
                                          int rbase,
                                          const float (&E)[46],
                                          int steps, int lane_c,
                                          float& q, float& C)
{
    const size_t sT = (size_t)B_N * K_N;
    auto row_of = [&](int i) -> int {
        int r = BWD ? (rbase - i) : (rbase + i);
        r = (r < 0) ? 0 : r;
        r = (r > T_LEN - 1) ? (T_LEN - 1) : r;   // physically valid; junk rows
        return r;                                 // only feed frozen steps
    };
    auto step = [&](bool on, float fv) {
        if (BWD) {
            const float u = q * __expf(fv);       // feat BEFORE matvec
            const float w = matvec46(E, u);
            q = on ? w : q;
        } else {
            const float w = matvec46(E, q);
            q = on ? w * __expf(fv) : q;          // feat AFTER matvec
        }
    };

    float f0[8], f1[8];
    #pragma unroll
    for (int i = 0; i < 8; ++i)
        f0[i] = fb[(size_t)row_of(i) * sT + lane_c];

    const int nfull = steps >> 4;                 // unmasked 16-step blocks
    #pragma unroll 1
    for (int blk = 0; blk < nfull; ++blk) {
        const int t0 = blk * 16;
        #pragma unroll
        for (int i = 0; i < 8; ++i)
            f1[i] = fb[(size_t)row_of(t0 + 8 + i) * sT + lane_c];
        #pragma unroll
        for (int i = 0; i < 8; ++i) {
            step(true, f0[i]);                    // cndmask folds away
            if (i == 3 || i == 7) renorm(q, C);
        }
        #pragma unroll
        for (int i = 0; i < 8; ++i)
            f0[i] = fb[(size_t)row_of(t0 + 16 + i) * sT + lane_c];
        #pragma unroll
        for (int i = 0; i < 8; ++i) {
            step(true, f1[i]);
            if (i == 3 || i == 7) renorm(q, C);
        }
    }
    const int rem = steps & 15;                   // one masked tail block
    if (rem) {
        const int t0 = nfull * 16;
        #pragma unroll
        for (int i = 0; i < 8; ++i)
            f1[i] = fb[(size_t)row_of(t0 + 8 + i) * sT + lane_c];
        #pragma unroll
        for (int i = 0; i < 8; ++i) {
            step(i < rem, f0[i]);
            if (i == 3 || i == 7) renorm(q, C);
        }
        if (rem > 8) {
            #pragma unroll
            for (int i = 0; i < 8; ++i) {
                step(8 + i < rem, f1[i]);
                if (i == 3 || i == 7) renorm(q, C);
            }
        }
    }
}

// ---- LPT sort: perm = batch ids by DESCENDING length (counting sort). ----
__global__ __launch_bounds__(1024)
void lpt_sort_kernel(const int* __restrict__ lengths, int* __restrict__ perm)
{
    __shared__ int hist[512];
    __shared__ int offs[512];
    const int tid = threadIdx.x;
    if (tid < 512) hist[tid] = 0;
    __syncthreads();
    const int len = lengths[tid];          // len in [1, 512]
    const int key = 512 - len;             // [0, 511], 0 = longest
    atomicAdd(&hist[key], 1);
    __syncthreads();
    if (tid < 512) offs[tid] = hist[tid];
    __syncthreads();
    for (int d = 1; d < 512; d <<= 1) {    // inclusive Hillis-Steele scan
        int v = 0;
        if (tid < 512 && tid >= d) v = offs[tid - d];
        __syncthreads();
        if (tid < 512) offs[tid] += v;
        __syncthreads();
    }
    const int p = atomicSub(&offs[key], 1) - 1;
    perm[p] = tid;
}

__global__ __launch_bounds__(128)
__attribute__((amdgpu_waves_per_eu(1, 1)))
void crf_fused_kernel(
    const float* __restrict__ feats,    // (T, B, K)
    const float* __restrict__ trans,    // (K, K)
    const int*   __restrict__ tags,     // (B, T)
    const int*   __restrict__ lengths,  // (B,)
    const int*   __restrict__ perm,     // (B,) LPT order
    float* __restrict__ out)
{
    const int b      = perm[blockIdx.x];          // LPT: longest first
    const int tid    = threadIdx.x;
    const int lane   = tid & 63;
    const int wid    = tid >> 6;                  // 0 = forward, 1 = backward
    const int len    = lengths[b];
    const int lm1    = len - 1;
    const int m      = (len + 1) >> 1;            // split point
    const int lane_c = (lane < K_N) ? lane : (K_N - 1);

    __shared__ __attribute__((aligned(16))) float sh_p[64];
    __shared__ float sh_cb;
    __shared__ float sh_gold;

    const float* fb = feats + (size_t)b * K_N;
    const size_t sT = (size_t)B_N * K_N;

    // Coefficients k = 0..45 (46,47 contribute 0 after the peel).
    // fwd: row lane of E = exp(trans); bwd: row lane of E^T.
    float E[46];
    if (wid == 0) {
        const float* tr = trans + lane_c * K_N;
        #pragma unroll
        for (int k = 0; k < 46; ++k) E[k] = __expf(tr[k]);
    } else {
        #pragma unroll
        for (int k = 0; k < 46; ++k) E[k] = __expf(trans[k * K_N + lane_c]);
    }

    float q, C = 0.0f;
    if (wid == 0) {
        // Peeled step 0: q_j = exp(trans[j,START] + feat0_j). Lane 46 -> 0.
        q = __expf(trans[lane_c * K_N + START_TAG] + fb[lane_c]);
        run_chain<0>(fb, 1, E, m - 1, lane_c, q, C);
    } else {
        q = __expf(trans[STOP_TAG * K_N + lane_c]);   // beta_len
        run_chain<1>(fb, lm1, E, len - m, lane_c, q, C);
    }
    renorm(q, C);   // bound q for the combine dot (q_0 == 1 after this)

    if (wid == 1) {
        // Gold path score, striped over t.
        float gsum = 0.0f;
        for (int t = lane; t < len; t += 64) {
            int next = tags[(size_t)b * T_LEN + t];
            int prev = (t == 0) ? START_TAG : tags[(size_t)b * T_LEN + t - 1];
            gsum += trans[next * K_N + prev] + fb[(size_t)t * sT + next];
        }
        #pragma unroll
        for (int off = 32; off >= 1; off >>= 1)
            gsum += __shfl_xor(gsum, off);

        sh_p[lane] = q;
        if (lane == 0) {
            sh_cb = C;
            int last = tags[(size_t)b * T_LEN + len - 1];
            sh_gold = gsum + trans[STOP_TAG * K_N + last];
        }
    }
    __syncthreads();

    if (wid == 0) {
        // log_z = C_f + C_b + log( sum_j q_j p_j ); j=46,47 terms are 0 by
        // construction (q_46 = 0, p_47 = 0), pads excluded by lane < K_N.
        float term = (lane < K_N) ? q * sh_p[lane] : 0.0f;
        #pragma unroll
        for (int off = 32; off >= 1; off >>= 1)
            term += __shfl_xor(term, off);
        if (lane == 0) {
            float log_z = C + sh_cb + __logf(term);
            atomicAdd(out, log_z - sh_gold);
        }
    }
}

extern "C" void kernel_launch(void* const* d_in, const int* in_sizes, int n_in,
                              void* d_out, int out_size, void* d_ws, size_t ws_size,
                              hipStream_t stream) {
    const float* feats   = (const float*)d_in[0];
    const float* trans   = (const float*)d_in[1];
    const int*   tags    = (const int*)d_in[2];
    const int*   lengths = (const int*)d_in[3];
    float* out = (float*)d_out;
    int*   perm = (int*)d_ws;                    // 4 KB of workspace

    hipMemsetAsync(out, 0, sizeof(float) * out_size, stream);
    lpt_sort_kernel<<<1, B_N, 0, stream>>>(lengths, perm);
    crf_fused_kernel<<<B_N, 128, 0, stream>>>(feats, trans, tags, lengths, perm, out);
}